// Round 7
// baseline (232.855 us; speedup 1.0000x reference)
//
#include <hip/hip_runtime.h>
#include <hip/hip_bf16.h>

// Problem constants (B,S,D,H fixed by setup_inputs)
#define B_  8
#define S_  1024
#define D_  768
#define H_  12
#define DH_ 64

typedef __attribute__((ext_vector_type(8))) short bf16x8;
typedef __attribute__((ext_vector_type(4))) float f32x4;
typedef __attribute__((ext_vector_type(16))) float f32x16;

__device__ inline short f2bf(float f) {
    unsigned u = __builtin_bit_cast(unsigned, f);
    u = (u + 0x7fffu + ((u >> 16) & 1u)) >> 16;   // RNE
    return (short)u;
}
__device__ inline float exp2_fast(float x) {
    float r; asm("v_exp_f32 %0, %1" : "=v"(r) : "v"(x)); return r;
}
__device__ inline unsigned cvt_pk_bf16(float lo, float hi) {
    unsigned r; asm("v_cvt_pk_bf16_f32 %0, %1, %2" : "=v"(r) : "v"(lo), "v"(hi)); return r;
}
__device__ inline float rcp_fast(float x) {
    float r; asm("v_rcp_f32 %0, %1" : "=v"(r) : "v"(x)); return r;
}
// Builtin permlane32_swap (compiler inserts the VALU->permlane hazard waits).
__device__ inline void plswap(unsigned& a, unsigned& b) {
    auto r = __builtin_amdgcn_permlane32_swap(a, b, false, false);
    a = r[0]; b = r[1];
}
__device__ inline float2 xhalves(float x) {
    unsigned u = __builtin_bit_cast(unsigned, x);
    auto r = __builtin_amdgcn_permlane32_swap(u, u, false, false);
    return make_float2(__builtin_bit_cast(float, r[0]),
                       __builtin_bit_cast(float, r[1]));
}

// ---------------------------------------------------------------------------
// Kernel 1 (v3): Y = relu(X @ W^T), X in {q,k,v} stacked along M (24576 rows).
// 128x128 tile, BK=32, DOUBLE-buffered XOR-swizzled zero-pad LDS (32 KB exactly
// -> 4-5 blocks/CU co-resident vs 1.4 before). One raw barrier per K-step.
// Layout per buffer: A[128 rows][4 slots of 16B], byte = row*64 + (slot^(row&3))*16;
// verified conflict-free for both b128 staging writes and b128 fragment reads.
// Staging: regs (4+4 f32x4/thread) loaded ~1.3 iterations ahead.
// ---------------------------------------------------------------------------
__global__ __launch_bounds__(256, 4) void proj_kernel(
    const float* __restrict__ q, const float* __restrict__ k,
    const float* __restrict__ v, const float* __restrict__ W,
    short* __restrict__ q1, short* __restrict__ k1, short* __restrict__ v1t)
{
    __shared__ __align__(16) char lds_raw[32768];   // [buf][A 8K | B 8K] x2

    int p  = blockIdx.x;
    int L  = (p & 7) * 144 + (p >> 3);   // XCD-chunked swizzle (1152 = 8*144)
    int mt = L / 6, nt = L % 6;
    int t  = mt >> 6;                    // 0=q,1=k,2=v
    int m0 = (mt & 63) << 7;
    int n0 = nt << 7;
    const float* X = (t == 0) ? q : (t == 1) ? k : v;

    int tid = threadIdx.x, lane = tid & 63, w = tid >> 6;
    int wr = w >> 1, wc = w & 1;
    int l15 = lane & 15, g = lane >> 4;

    int srow = tid >> 1, h = tid & 1;    // staging: row, 16-f32 half
    const float* ax = X + (size_t)(m0 + srow) * D_ + h * 16;
    const float* bx = W + (size_t)(n0 + srow) * D_ + h * 16;

    // swizzled staging-write byte offsets (slots 2h, 2h+1)
    int wb0 = srow * 64 + ((((h << 1) | 0) ^ (srow & 3)) << 4);
    int wb1 = srow * 64 + ((((h << 1) | 1) ^ (srow & 3)) << 4);
    // swizzled fragment-read slot offset (slot g ^ (row&3), row&3 == l15&3)
    int fs = (g ^ (l15 & 3)) << 4;

    f32x4 la[4], lb[4];
#define LOADAB(step) do { int _c = (step) * 32; \
        la[0] = *(const f32x4*)(ax + _c);      la[1] = *(const f32x4*)(ax + _c + 4); \
        la[2] = *(const f32x4*)(ax + _c + 8);  la[3] = *(const f32x4*)(ax + _c + 12); \
        lb[0] = *(const f32x4*)(bx + _c);      lb[1] = *(const f32x4*)(bx + _c + 4); \
        lb[2] = *(const f32x4*)(bx + _c + 8);  lb[3] = *(const f32x4*)(bx + _c + 12); \
    } while (0)
#define CONVW(bufbase) do { \
        uint4 ua0, ua1, ub0, ub1; \
        ua0.x = cvt_pk_bf16(la[0][0], la[0][1]); ua0.y = cvt_pk_bf16(la[0][2], la[0][3]); \
        ua0.z = cvt_pk_bf16(la[1][0], la[1][1]); ua0.w = cvt_pk_bf16(la[1][2], la[1][3]); \
        ua1.x = cvt_pk_bf16(la[2][0], la[2][1]); ua1.y = cvt_pk_bf16(la[2][2], la[2][3]); \
        ua1.z = cvt_pk_bf16(la[3][0], la[3][1]); ua1.w = cvt_pk_bf16(la[3][2], la[3][3]); \
        ub0.x = cvt_pk_bf16(lb[0][0], lb[0][1]); ub0.y = cvt_pk_bf16(lb[0][2], lb[0][3]); \
        ub0.z = cvt_pk_bf16(lb[1][0], lb[1][1]); ub0.w = cvt_pk_bf16(lb[1][2], lb[1][3]); \
        ub1.x = cvt_pk_bf16(lb[2][0], lb[2][1]); ub1.y = cvt_pk_bf16(lb[2][2], lb[2][3]); \
        ub1.z = cvt_pk_bf16(lb[3][0], lb[3][1]); ub1.w = cvt_pk_bf16(lb[3][2], lb[3][3]); \
        *(uint4*)(lds_raw + (bufbase) + wb0)        = ua0; \
        *(uint4*)(lds_raw + (bufbase) + wb1)        = ua1; \
        *(uint4*)(lds_raw + (bufbase) + 8192 + wb0) = ub0; \
        *(uint4*)(lds_raw + (bufbase) + 8192 + wb1) = ub1; \
    } while (0)

    f32x4 acc[4][4];
    #pragma unroll
    for (int m = 0; m < 4; m++)
        #pragma unroll
        for (int n = 0; n < 4; n++) acc[m][n] = (f32x4){0.f, 0.f, 0.f, 0.f};

    // prologue: step0 -> buf0; step1 loads in regs
    LOADAB(0);
    CONVW(0);
    LOADAB(1);
    asm volatile("s_waitcnt lgkmcnt(0)" ::: "memory");
    __builtin_amdgcn_s_barrier();
    asm volatile("" ::: "memory");

    #pragma unroll 2
    for (int s = 0; s < 24; ++s) {
        if (s < 23) CONVW(((s + 1) & 1) << 14);     // stage step s+1 (other buf)
        if (s < 22) LOADAB(s + 2);                  // issue loads for step s+2
        const char* bufp = lds_raw + ((s & 1) << 14);
        bf16x8 af[4], bfv[4];
        #pragma unroll
        for (int m = 0; m < 4; m++)
            af[m] = *(const bf16x8*)(bufp + (wr * 64 + m * 16 + l15) * 64 + fs);
        #pragma unroll
        for (int n = 0; n < 4; n++)
            bfv[n] = *(const bf16x8*)(bufp + 8192 + (wc * 64 + n * 16 + l15) * 64 + fs);
        __builtin_amdgcn_s_setprio(1);
        #pragma unroll
        for (int m = 0; m < 4; m++)
            #pragma unroll
            for (int n = 0; n < 4; n++)
                acc[m][n] = __builtin_amdgcn_mfma_f32_16x16x32_bf16(
                    af[m], bfv[n], acc[m][n], 0, 0, 0);
        __builtin_amdgcn_s_setprio(0);
        if (s < 23) {
            asm volatile("s_waitcnt lgkmcnt(0)" ::: "memory");
            __builtin_amdgcn_s_barrier();   // writes visible; reads of buf done
            asm volatile("" ::: "memory");
        }
    }
#undef LOADAB
#undef CONVW

    // Epilogue: relu(+scale) -> bf16 -> swizzled-LDS transpose -> b128 stores.
    // Ts: 128 rows x 16 slots of 16B; byte = r*256 + ((slot^(r&15))<<4) + (c&7)*2
    __syncthreads();
    const float sc1 = (t == 1) ? 0.18033688011112793f : 1.0f;  // 1/8*log2(e)
    #pragma unroll
    for (int m = 0; m < 4; m++) {
        int rb = wr * 64 + m * 16 + (g << 2);
        #pragma unroll
        for (int n = 0; n < 4; n++) {
            int cb = wc * 64 + n * 16 + l15;
            #pragma unroll
            for (int r = 0; r < 4; r++) {
                short vv = f2bf(fmaxf(acc[m][n][r], 0.f) * sc1);
                int rr = (t == 2) ? cb : rb + r;     // v: store transposed
                int cc = (t == 2) ? rb + r : cb;
                *(short*)(lds_raw + rr * 256 + (((cc >> 3) ^ (rr & 15)) << 4)
                          + ((cc & 7) << 1)) = vv;
            }
        }
    }
    __syncthreads();
    int row = tid >> 1;
    int c0  = (tid & 1) << 6;
    bf16x8 ov[8];
    #pragma unroll
    for (int j = 0; j < 8; j++)
        ov[j] = *(const bf16x8*)(lds_raw + row * 256 +
                 ((((c0 >> 3) + j) ^ (row & 15)) << 4));
    if (t == 2) {
        int gc = n0 + row;
        int hh2 = gc >> 6, dh = gc & 63;
        int bb = m0 >> 10, s0 = m0 & 1023;
        short* dst = v1t + (((size_t)bb * H_ + hh2) * DH_ + dh) * S_ + s0 + c0;
        #pragma unroll
        for (int j = 0; j < 8; j++) *(bf16x8*)(dst + j * 8) = ov[j];
    } else {
        int m = m0 + row;
        int bb = m >> 10, ss = m & 1023;
        int hh2 = (n0 >> 6) + (tid & 1);
        short* dst = (t ? k1 : q1) + (((size_t)bb * H_ + hh2) * S_ + ss) * DH_;
        #pragma unroll
        for (int j = 0; j < 8; j++) *(bf16x8*)(dst + j * 8) = ov[j];
    }
}

// ---------------------------------------------------------------------------
// Kernel 2 (v5): flash attention, swapped-QK^T 32x32x16, block-cooperative
// LDS-staged K/V (unchanged from round 6 -- passing, fast).
// ---------------------------------------------------------------------------
__global__ __launch_bounds__(256, 3) void attn_kernel(
    const short* __restrict__ q1, const short* __restrict__ k1,
    const short* __restrict__ v1t, float* __restrict__ out)
{
    __shared__ short Klds[2][4096];   // [buf][64 kv rows][64 dh], swizzled
    __shared__ short Vlds[2][4096];   // [buf][64 dh rows][64 kv], swizzled
    __shared__ float lsum_lds[4][32];

    int d    = blockIdx.x;                       // 0..767
    int head = (d & 7) + ((d >> 6) << 3);        // same head -> same XCD
    int qi   = (d >> 3) & 7;
    int bb   = head / H_, hh = head % H_;

    int tid = threadIdx.x, lane = tid & 63, w = tid >> 6;
    int l31 = lane & 31, hi = lane >> 5;
    int qbase = (qi * 4 + w) * 32;

    const short* Qp = q1  + (size_t)head * S_ * DH_;
    const short* Kp = k1  + (size_t)head * S_ * DH_;
    const short* Vp = v1t + (size_t)head * DH_ * S_;

    // staging geometry: thread -> (row r, 16B slot c / c+4)
    int sr = tid >> 2, sc = tid & 3;
    int swz0 = sr * 128 + ((sc       ^ (sr & 7)) << 4);
    int swz1 = sr * 128 + (((sc + 4) ^ (sr & 7)) << 4);

    bf16x8 stK0, stK1, stV0, stV1;

#define LOADST(kvb) do { \
        const short* _kg = Kp + (size_t)((kvb) + sr) * DH_; \
        const short* _vg = Vp + (size_t)sr * S_ + (kvb); \
        stK0 = *(const bf16x8*)(_kg + sc * 8); \
        stK1 = *(const bf16x8*)(_kg + (sc + 4) * 8); \
        stV0 = *(const bf16x8*)(_vg + sc * 8); \
        stV1 = *(const bf16x8*)(_vg + (sc + 4) * 8); \
    } while (0)
#define WRITEST(buf) do { \
        char* _kb = (char*)&Klds[buf][0]; \
        char* _vb = (char*)&Vlds[buf][0]; \
        *(bf16x8*)(_kb + swz0) = stK0; \
        *(bf16x8*)(_kb + swz1) = stK1; \
        *(bf16x8*)(_vb + swz0) = stV0; \
        *(bf16x8*)(_vb + swz1) = stV1; \
    } while (0)

    bf16x8 qf[4];
    #pragma unroll
    for (int kb = 0; kb < 4; kb++)
        qf[kb] = *(const bf16x8*)(Qp + (size_t)(qbase + l31) * DH_ + kb * 16 + hi * 8);

    f32x16 o0, o1;
    #pragma unroll
    for (int r = 0; r < 16; r++) { o0[r] = 0.f; o1[r] = 0.f; }
    float mreg = -1e30f, lsum = 0.f;

    int xk = l31 & 7;   // row-XOR for fragment reads

    auto subtile = [&](int cur, int j) {
        const char* Kt = (const char*)&Klds[cur][0];
        const char* Vt = (const char*)&Vlds[cur][0];
        int rK = (32 * j + l31) * 128;
        bf16x8 kf0 = *(const bf16x8*)(Kt + rK + (((0 + hi) ^ xk) << 4));
        bf16x8 kf1 = *(const bf16x8*)(Kt + rK + (((2 + hi) ^ xk) << 4));
        bf16x8 kf2 = *(const bf16x8*)(Kt + rK + (((4 + hi) ^ xk) << 4));
        bf16x8 kf3 = *(const bf16x8*)(Kt + rK + (((6 + hi) ^ xk) << 4));
        int rV0 = l31 * 128, rV1 = (32 + l31) * 128;
        int s0 = ((4 * j + hi) ^ xk) << 4, s1 = ((4 * j + 2 + hi) ^ xk) << 4;
        bf16x8 vf00 = *(const bf16x8*)(Vt + rV0 + s0);
        bf16x8 vf01 = *(const bf16x8*)(Vt + rV0 + s1);
        bf16x8 vf10 = *(const bf16x8*)(Vt + rV1 + s0);
        bf16x8 vf11 = *(const bf16x8*)(Vt + rV1 + s1);

        f32x16 s;
        #pragma unroll
        for (int r = 0; r < 16; r++) s[r] = 0.f;
        __builtin_amdgcn_s_setprio(1);
        s = __builtin_amdgcn_mfma_f32_32x32x16_bf16(kf0, qf[0], s, 0, 0, 0);
        s = __builtin_amdgcn_mfma_f32_32x32x16_bf16(kf1, qf[1], s, 0, 0, 0);
        s = __builtin_amdgcn_mfma_f32_32x32x16_bf16(kf2, qf[2], s, 0, 0, 0);
        s = __builtin_amdgcn_mfma_f32_32x32x16_bf16(kf3, qf[3], s, 0, 0, 0);
        __builtin_amdgcn_s_setprio(0);

        float t0 = fmaxf(s[0], s[1]),   t1 = fmaxf(s[2], s[3]);
        float t2 = fmaxf(s[4], s[5]),   t3 = fmaxf(s[6], s[7]);
        float t4 = fmaxf(s[8], s[9]),   t5 = fmaxf(s[10], s[11]);
        float t6 = fmaxf(s[12], s[13]), t7 = fmaxf(s[14], s[15]);
        float u0 = fmaxf(t0, t1), u1 = fmaxf(t2, t3);
        float u2 = fmaxf(t4, t5), u3 = fmaxf(t6, t7);
        float pmax = fmaxf(fmaxf(u0, u1), fmaxf(u2, u3));
        float2 ph = xhalves(pmax);
        pmax = fmaxf(ph.x, ph.y);

        if (!__all(pmax <= mreg + 8.f)) {       // defer-max (T13), log2 domain
            float mn = fmaxf(mreg, pmax);
            float sc_ = exp2_fast(mreg - mn);
            mreg = mn; lsum *= sc_;
            if (hi == 0) lsum_lds[w][l31] = sc_;
            asm volatile("s_waitcnt lgkmcnt(0)" ::: "memory");
            #pragma unroll
            for (int r = 0; r < 16; r++) {
                int crow = (r & 3) + ((r >> 2) << 3) + (hi << 2);
                float srw = lsum_lds[w][crow];
                o0[r] *= srw; o1[r] *= srw;
            }
        }

        #pragma unroll
        for (int r = 0; r < 16; r++) s[r] = exp2_fast(s[r] - mreg);

        float a0 = s[0] + s[1],   a1 = s[2] + s[3];
        float a2 = s[4] + s[5],   a3 = s[6] + s[7];
        float a4 = s[8] + s[9],   a5 = s[10] + s[11];
        float a6 = s[12] + s[13], a7 = s[14] + s[15];
        float rsum = ((a0 + a1) + (a2 + a3)) + ((a4 + a5) + (a6 + a7));
        float2 rh = xhalves(rsum);
        lsum += rh.x + rh.y;

        unsigned c0 = cvt_pk_bf16(s[0], s[1]);
        unsigned c1 = cvt_pk_bf16(s[2], s[3]);
        unsigned c2 = cvt_pk_bf16(s[4], s[5]);
        unsigned c3 = cvt_pk_bf16(s[6], s[7]);
        unsigned c4 = cvt_pk_bf16(s[8], s[9]);
        unsigned c5 = cvt_pk_bf16(s[10], s[11]);
        unsigned c6 = cvt_pk_bf16(s[12], s[13]);
        unsigned c7 = cvt_pk_bf16(s[14], s[15]);
        plswap(c0, c2);
        plswap(c1, c3);
        plswap(c4, c6);
        plswap(c5, c7);

        union U { unsigned u[4]; bf16x8 v; };
        U f0, f1;
        f0.u[0] = c0; f0.u[1] = c1; f0.u[2] = c2; f0.u[3] = c3;
        f1.u[0] = c4; f1.u[1] = c5; f1.u[2] = c6; f1.u[3] = c7;

        __builtin_amdgcn_s_setprio(1);
        o0 = __builtin_amdgcn_mfma_f32_32x32x16_bf16(f0.v, vf00, o0, 0, 0, 0);
        o0 = __builtin_amdgcn_mfma_f32_32x32x16_bf16(f1.v, vf01, o0, 0, 0, 0);
        o1 = __builtin_amdgcn_mfma_f32_32x32x16_bf16(f0.v, vf10, o1, 0, 0, 0);
        o1 = __builtin_amdgcn_mfma_f32_32x32x16_bf16(f1.v, vf11, o1, 0, 0, 0);
        __builtin_amdgcn_s_setprio(0);
    };

    // ---- pipeline prologue ----
    LOADST(0);
    WRITEST(0);
    LOADST(64);
    asm volatile("s_waitcnt lgkmcnt(0)" ::: "memory");
    __builtin_amdgcn_s_barrier();
    asm volatile("" ::: "memory");

    int cur = 0;
    for (int t = 0; t < 16; t++) {
        if (t < 15) {
            WRITEST(cur ^ 1);
            if (t < 14) LOADST((t + 2) * 64);
        }
        subtile(cur, 0);
        subtile(cur, 1);
        if (t < 15) {
            asm volatile("" ::: "memory");
            asm volatile("s_waitcnt lgkmcnt(0)" ::: "memory");
            __builtin_amdgcn_s_barrier();
            asm volatile("" ::: "memory");
        }
        cur ^= 1;
    }
#undef LOADST
#undef WRITEST

    if (hi == 0) lsum_lds[w][l31] = lsum;
    asm volatile("s_waitcnt lgkmcnt(0)" ::: "memory");
    #pragma unroll
    for (int r = 0; r < 16; r++) {
        int crow = (r & 3) + ((r >> 2) << 3) + (hi << 2);
        float inv = rcp_fast(lsum_lds[w][crow]);
        float* op = out + ((size_t)(bb * S_ + qbase + crow)) * D_ + hh * DH_ + l31;
        op[0]  = o0[r] * inv;
        op[32] = o1[r] * inv;
    }
}

// ---------------------------------------------------------------------------
// Kernel 3 (v2): y = LN(2*out + q) * gamma + beta; 192 thr/row, f32x4 loads.
// ---------------------------------------------------------------------------
__global__ __launch_bounds__(192) void ln_kernel(
    const float* __restrict__ qin, const float* __restrict__ gamma,
    const float* __restrict__ beta, float* __restrict__ out)
{
    int row = blockIdx.x;
    int tid = threadIdx.x;
    size_t base = (size_t)row * D_ + tid * 4;

    f32x4 o  = *(const f32x4*)(out + base);
    f32x4 qv = *(const f32x4*)(qin + base);
    f32x4 x;
    float sum = 0.f, sq = 0.f;
    #pragma unroll
    for (int i = 0; i < 4; i++) {
        x[i] = 2.f * o[i] + qv[i];
        sum += x[i];
        sq  += x[i] * x[i];
    }
    #pragma unroll
    for (int msk = 1; msk < 64; msk <<= 1) {
        sum += __shfl_xor(sum, msk);
        sq  += __shfl_xor(sq, msk);
    }
    __shared__ float s1[3], s2[3];
    if ((tid & 63) == 0) { s1[tid >> 6] = sum; s2[tid >> 6] = sq; }
    __syncthreads();
    sum = s1[0] + s1[1] + s1[2];
    sq  = s2[0] + s2[1] + s2[2];
    float mu   = sum * (1.f / D_);
    float var  = sq * (1.f / D_) - mu * mu;
    float rstd = rsqrtf(var + 1e-5f);
    f32x4 g = *(const f32x4*)(gamma + tid * 4);
    f32x4 b = *(const f32x4*)(beta + tid * 4);
    f32x4 y;
    #pragma unroll
    for (int i = 0; i < 4; i++)
        y[i] = (x[i] - mu) * rstd * g[i] + b[i];
    *(f32x4*)(out + base) = y;
}

// ---------------------------------------------------------------------------
extern "C" void kernel_launch(void* const* d_in, const int* in_sizes, int n_in,
                              void* d_out, int out_size, void* d_ws, size_t ws_size,
                              hipStream_t stream)
{
    const float* q     = (const float*)d_in[0];
    const float* k     = (const float*)d_in[1];
    const float* v     = (const float*)d_in[2];
    const float* W     = (const float*)d_in[3];
    const float* gamma = (const float*)d_in[4];
    const float* beta  = (const float*)d_in[5];

    size_t per = (size_t)B_ * H_ * S_ * DH_;
    short* q1  = (short*)d_ws;
    short* k1  = q1 + per;
    short* v1t = k1 + per;
    float* out = (float*)d_out;

    proj_kernel<<<dim3(1152), dim3(256), 0, stream>>>(q, k, v, W, q1, k1, v1t);
    attn_kernel<<<dim3(768), dim3(256), 0, stream>>>(q1, k1, v1t, out);
    ln_kernel<<<dim3(B_ * S_), dim3(192), 0, stream>>>(q, gamma, beta, out);
}

// Round 8
// 130.176 us; speedup vs baseline: 1.7888x; 1.7888x over previous
//
#include <hip/hip_runtime.h>
#include <hip/hip_bf16.h>

// Problem constants (B,S,D,H fixed by setup_inputs)
#define B_  8
#define S_  1024
#define D_  768
#define H_  12
#define DH_ 64

typedef __attribute__((ext_vector_type(8))) short bf16x8;
typedef __attribute__((ext_vector_type(4))) float f32x4;
typedef __attribute__((ext_vector_type(16))) float f32x16;

__device__ inline short f2bf(float f) {
    unsigned u = __builtin_bit_cast(unsigned, f);
    u = (u + 0x7fffu + ((u >> 16) & 1u)) >> 16;   // RNE
    return (short)u;
}
__device__ inline float exp2_fast(float x) {
    float r; asm("v_exp_f32 %0, %1" : "=v"(r) : "v"(x)); return r;
}
__device__ inline unsigned cvt_pk_bf16(float lo, float hi) {
    unsigned r; asm("v_cvt_pk_bf16_f32 %0, %1, %2" : "=v"(r) : "v"(lo), "v"(hi)); return r;
}
__device__ inline float rcp_fast(float x) {
    float r; asm("v_rcp_f32 %0, %1" : "=v"(r) : "v"(x)); return r;
}
// Builtin permlane32_swap (compiler inserts the VALU->permlane hazard waits).
__device__ inline void plswap(unsigned& a, unsigned& b) {
    auto r = __builtin_amdgcn_permlane32_swap(a, b, false, false);
    a = r[0]; b = r[1];
}
__device__ inline float2 xhalves(float x) {
    unsigned u = __builtin_bit_cast(unsigned, x);
    auto r = __builtin_amdgcn_permlane32_swap(u, u, false, false);
    return make_float2(__builtin_bit_cast(float, r[0]),
                       __builtin_bit_cast(float, r[1]));
}

// ---------------------------------------------------------------------------
// Kernel 1 (v3b): Y = relu(X @ W^T), X in {q,k,v} stacked along M (24576 rows).
// 128x128 tile, BK=32, double-buffered XOR-swizzled zero-pad LDS (32 KB).
// NOTE: plain __launch_bounds__(256). R7's (256,4) set waves-per-eu range
// 4..8 and the allocator clamped to 64 VGPRs (8-wave step) -> spilled la/lb
// every K-step (WRITE_SIZE 37->358 MB, 2.5x slowdown). Unconstrained, this
// kernel allocates ~116 VGPRs, no spill (R6 evidence), <=128 -> 4 waves/SIMD.
// ---------------------------------------------------------------------------
__global__ __launch_bounds__(256) void proj_kernel(
    const float* __restrict__ q, const float* __restrict__ k,
    const float* __restrict__ v, const float* __restrict__ W,
    short* __restrict__ q1, short* __restrict__ k1, short* __restrict__ v1t)
{
    __shared__ __align__(16) char lds_raw[32768];   // [buf][A 8K | B 8K] x2

    int p  = blockIdx.x;
    int L  = (p & 7) * 144 + (p >> 3);   // XCD-chunked swizzle (1152 = 8*144)
    int mt = L / 6, nt = L % 6;
    int t  = mt >> 6;                    // 0=q,1=k,2=v
    int m0 = (mt & 63) << 7;
    int n0 = nt << 7;
    const float* X = (t == 0) ? q : (t == 1) ? k : v;

    int tid = threadIdx.x, lane = tid & 63, w = tid >> 6;
    int wr = w >> 1, wc = w & 1;
    int l15 = lane & 15, g = lane >> 4;

    int srow = tid >> 1, h = tid & 1;    // staging: row, 16-f32 half
    const float* ax = X + (size_t)(m0 + srow) * D_ + h * 16;
    const float* bx = W + (size_t)(n0 + srow) * D_ + h * 16;

    // swizzled staging-write byte offsets (slots 2h, 2h+1)
    int wb0 = srow * 64 + ((((h << 1) | 0) ^ (srow & 3)) << 4);
    int wb1 = srow * 64 + ((((h << 1) | 1) ^ (srow & 3)) << 4);
    // swizzled fragment-read slot offset (slot g ^ (row&3), row&3 == l15&3)
    int fs = (g ^ (l15 & 3)) << 4;

    f32x4 la[4], lb[4];
#define LOADAB(step) do { int _c = (step) * 32; \
        la[0] = *(const f32x4*)(ax + _c);      la[1] = *(const f32x4*)(ax + _c + 4); \
        la[2] = *(const f32x4*)(ax + _c + 8);  la[3] = *(const f32x4*)(ax + _c + 12); \
        lb[0] = *(const f32x4*)(bx + _c);      lb[1] = *(const f32x4*)(bx + _c + 4); \
        lb[2] = *(const f32x4*)(bx + _c + 8);  lb[3] = *(const f32x4*)(bx + _c + 12); \
    } while (0)
#define CONVW(bufbase) do { \
        uint4 ua0, ua1, ub0, ub1; \
        ua0.x = cvt_pk_bf16(la[0][0], la[0][1]); ua0.y = cvt_pk_bf16(la[0][2], la[0][3]); \
        ua0.z = cvt_pk_bf16(la[1][0], la[1][1]); ua0.w = cvt_pk_bf16(la[1][2], la[1][3]); \
        ua1.x = cvt_pk_bf16(la[2][0], la[2][1]); ua1.y = cvt_pk_bf16(la[2][2], la[2][3]); \
        ua1.z = cvt_pk_bf16(la[3][0], la[3][1]); ua1.w = cvt_pk_bf16(la[3][2], la[3][3]); \
        ub0.x = cvt_pk_bf16(lb[0][0], lb[0][1]); ub0.y = cvt_pk_bf16(lb[0][2], lb[0][3]); \
        ub0.z = cvt_pk_bf16(lb[1][0], lb[1][1]); ub0.w = cvt_pk_bf16(lb[1][2], lb[1][3]); \
        ub1.x = cvt_pk_bf16(lb[2][0], lb[2][1]); ub1.y = cvt_pk_bf16(lb[2][2], lb[2][3]); \
        ub1.z = cvt_pk_bf16(lb[3][0], lb[3][1]); ub1.w = cvt_pk_bf16(lb[3][2], lb[3][3]); \
        *(uint4*)(lds_raw + (bufbase) + wb0)        = ua0; \
        *(uint4*)(lds_raw + (bufbase) + wb1)        = ua1; \
        *(uint4*)(lds_raw + (bufbase) + 8192 + wb0) = ub0; \
        *(uint4*)(lds_raw + (bufbase) + 8192 + wb1) = ub1; \
    } while (0)

    f32x4 acc[4][4];
    #pragma unroll
    for (int m = 0; m < 4; m++)
        #pragma unroll
        for (int n = 0; n < 4; n++) acc[m][n] = (f32x4){0.f, 0.f, 0.f, 0.f};

    // prologue: step0 -> buf0; step1 loads in regs
    LOADAB(0);
    CONVW(0);
    LOADAB(1);
    asm volatile("s_waitcnt lgkmcnt(0)" ::: "memory");
    __builtin_amdgcn_s_barrier();
    asm volatile("" ::: "memory");

    #pragma unroll 2
    for (int s = 0; s < 24; ++s) {
        if (s < 23) CONVW(((s + 1) & 1) << 14);     // stage step s+1 (other buf)
        if (s < 22) LOADAB(s + 2);                  // issue loads for step s+2
        const char* bufp = lds_raw + ((s & 1) << 14);
        bf16x8 af[4], bfv[4];
        #pragma unroll
        for (int m = 0; m < 4; m++)
            af[m] = *(const bf16x8*)(bufp + (wr * 64 + m * 16 + l15) * 64 + fs);
        #pragma unroll
        for (int n = 0; n < 4; n++)
            bfv[n] = *(const bf16x8*)(bufp + 8192 + (wc * 64 + n * 16 + l15) * 64 + fs);
        __builtin_amdgcn_s_setprio(1);
        #pragma unroll
        for (int m = 0; m < 4; m++)
            #pragma unroll
            for (int n = 0; n < 4; n++)
                acc[m][n] = __builtin_amdgcn_mfma_f32_16x16x32_bf16(
                    af[m], bfv[n], acc[m][n], 0, 0, 0);
        __builtin_amdgcn_s_setprio(0);
        if (s < 23) {
            asm volatile("s_waitcnt lgkmcnt(0)" ::: "memory");
            __builtin_amdgcn_s_barrier();   // writes visible; reads of buf done
            asm volatile("" ::: "memory");
        }
    }
#undef LOADAB
#undef CONVW

    // Epilogue: relu(+scale) -> bf16 -> swizzled-LDS transpose -> b128 stores.
    // Ts: 128 rows x 16 slots of 16B; byte = r*256 + ((slot^(r&15))<<4) + (c&7)*2
    __syncthreads();
    const float sc1 = (t == 1) ? 0.18033688011112793f : 1.0f;  // 1/8*log2(e)
    #pragma unroll
    for (int m = 0; m < 4; m++) {
        int rb = wr * 64 + m * 16 + (g << 2);
        #pragma unroll
        for (int n = 0; n < 4; n++) {
            int cb = wc * 64 + n * 16 + l15;
            #pragma unroll
            for (int r = 0; r < 4; r++) {
                short vv = f2bf(fmaxf(acc[m][n][r], 0.f) * sc1);
                int rr = (t == 2) ? cb : rb + r;     // v: store transposed
                int cc = (t == 2) ? rb + r : cb;
                *(short*)(lds_raw + rr * 256 + (((cc >> 3) ^ (rr & 15)) << 4)
                          + ((cc & 7) << 1)) = vv;
            }
        }
    }
    __syncthreads();
    int row = tid >> 1;
    int c0  = (tid & 1) << 6;
    bf16x8 ov[8];
    #pragma unroll
    for (int j = 0; j < 8; j++)
        ov[j] = *(const bf16x8*)(lds_raw + row * 256 +
                 ((((c0 >> 3) + j) ^ (row & 15)) << 4));
    if (t == 2) {
        int gc = n0 + row;
        int hh2 = gc >> 6, dh = gc & 63;
        int bb = m0 >> 10, s0 = m0 & 1023;
        short* dst = v1t + (((size_t)bb * H_ + hh2) * DH_ + dh) * S_ + s0 + c0;
        #pragma unroll
        for (int j = 0; j < 8; j++) *(bf16x8*)(dst + j * 8) = ov[j];
    } else {
        int m = m0 + row;
        int bb = m >> 10, ss = m & 1023;
        int hh2 = (n0 >> 6) + (tid & 1);
        short* dst = (t ? k1 : q1) + (((size_t)bb * H_ + hh2) * S_ + ss) * DH_;
        #pragma unroll
        for (int j = 0; j < 8; j++) *(bf16x8*)(dst + j * 8) = ov[j];
    }
}

// ---------------------------------------------------------------------------
// Kernel 2 (v5): flash attention, swapped-QK^T 32x32x16, block-cooperative
// LDS-staged K/V (unchanged from round 6 -- passing, fast).
// ---------------------------------------------------------------------------
__global__ __launch_bounds__(256, 3) void attn_kernel(
    const short* __restrict__ q1, const short* __restrict__ k1,
    const short* __restrict__ v1t, float* __restrict__ out)
{
    __shared__ short Klds[2][4096];   // [buf][64 kv rows][64 dh], swizzled
    __shared__ short Vlds[2][4096];   // [buf][64 dh rows][64 kv], swizzled
    __shared__ float lsum_lds[4][32];

    int d    = blockIdx.x;                       // 0..767
    int head = (d & 7) + ((d >> 6) << 3);        // same head -> same XCD
    int qi   = (d >> 3) & 7;
    int bb   = head / H_, hh = head % H_;

    int tid = threadIdx.x, lane = tid & 63, w = tid >> 6;
    int l31 = lane & 31, hi = lane >> 5;
    int qbase = (qi * 4 + w) * 32;

    const short* Qp = q1  + (size_t)head * S_ * DH_;
    const short* Kp = k1  + (size_t)head * S_ * DH_;
    const short* Vp = v1t + (size_t)head * DH_ * S_;

    // staging geometry: thread -> (row r, 16B slot c / c+4)
    int sr = tid >> 2, sc = tid & 3;
    int swz0 = sr * 128 + ((sc       ^ (sr & 7)) << 4);
    int swz1 = sr * 128 + (((sc + 4) ^ (sr & 7)) << 4);

    bf16x8 stK0, stK1, stV0, stV1;

#define LOADST(kvb) do { \
        const short* _kg = Kp + (size_t)((kvb) + sr) * DH_; \
        const short* _vg = Vp + (size_t)sr * S_ + (kvb); \
        stK0 = *(const bf16x8*)(_kg + sc * 8); \
        stK1 = *(const bf16x8*)(_kg + (sc + 4) * 8); \
        stV0 = *(const bf16x8*)(_vg + sc * 8); \
        stV1 = *(const bf16x8*)(_vg + (sc + 4) * 8); \
    } while (0)
#define WRITEST(buf) do { \
        char* _kb = (char*)&Klds[buf][0]; \
        char* _vb = (char*)&Vlds[buf][0]; \
        *(bf16x8*)(_kb + swz0) = stK0; \
        *(bf16x8*)(_kb + swz1) = stK1; \
        *(bf16x8*)(_vb + swz0) = stV0; \
        *(bf16x8*)(_vb + swz1) = stV1; \
    } while (0)

    bf16x8 qf[4];
    #pragma unroll
    for (int kb = 0; kb < 4; kb++)
        qf[kb] = *(const bf16x8*)(Qp + (size_t)(qbase + l31) * DH_ + kb * 16 + hi * 8);

    f32x16 o0, o1;
    #pragma unroll
    for (int r = 0; r < 16; r++) { o0[r] = 0.f; o1[r] = 0.f; }
    float mreg = -1e30f, lsum = 0.f;

    int xk = l31 & 7;   // row-XOR for fragment reads

    auto subtile = [&](int cur, int j) {
        const char* Kt = (const char*)&Klds[cur][0];
        const char* Vt = (const char*)&Vlds[cur][0];
        int rK = (32 * j + l31) * 128;
        bf16x8 kf0 = *(const bf16x8*)(Kt + rK + (((0 + hi) ^ xk) << 4));
        bf16x8 kf1 = *(const bf16x8*)(Kt + rK + (((2 + hi) ^ xk) << 4));
        bf16x8 kf2 = *(const bf16x8*)(Kt + rK + (((4 + hi) ^ xk) << 4));
        bf16x8 kf3 = *(const bf16x8*)(Kt + rK + (((6 + hi) ^ xk) << 4));
        int rV0 = l31 * 128, rV1 = (32 + l31) * 128;
        int s0 = ((4 * j + hi) ^ xk) << 4, s1 = ((4 * j + 2 + hi) ^ xk) << 4;
        bf16x8 vf00 = *(const bf16x8*)(Vt + rV0 + s0);
        bf16x8 vf01 = *(const bf16x8*)(Vt + rV0 + s1);
        bf16x8 vf10 = *(const bf16x8*)(Vt + rV1 + s0);
        bf16x8 vf11 = *(const bf16x8*)(Vt + rV1 + s1);

        f32x16 s;
        #pragma unroll
        for (int r = 0; r < 16; r++) s[r] = 0.f;
        __builtin_amdgcn_s_setprio(1);
        s = __builtin_amdgcn_mfma_f32_32x32x16_bf16(kf0, qf[0], s, 0, 0, 0);
        s = __builtin_amdgcn_mfma_f32_32x32x16_bf16(kf1, qf[1], s, 0, 0, 0);
        s = __builtin_amdgcn_mfma_f32_32x32x16_bf16(kf2, qf[2], s, 0, 0, 0);
        s = __builtin_amdgcn_mfma_f32_32x32x16_bf16(kf3, qf[3], s, 0, 0, 0);
        __builtin_amdgcn_s_setprio(0);

        float t0 = fmaxf(s[0], s[1]),   t1 = fmaxf(s[2], s[3]);
        float t2 = fmaxf(s[4], s[5]),   t3 = fmaxf(s[6], s[7]);
        float t4 = fmaxf(s[8], s[9]),   t5 = fmaxf(s[10], s[11]);
        float t6 = fmaxf(s[12], s[13]), t7 = fmaxf(s[14], s[15]);
        float u0 = fmaxf(t0, t1), u1 = fmaxf(t2, t3);
        float u2 = fmaxf(t4, t5), u3 = fmaxf(t6, t7);
        float pmax = fmaxf(fmaxf(u0, u1), fmaxf(u2, u3));
        float2 ph = xhalves(pmax);
        pmax = fmaxf(ph.x, ph.y);

        if (!__all(pmax <= mreg + 8.f)) {       // defer-max (T13), log2 domain
            float mn = fmaxf(mreg, pmax);
            float sc_ = exp2_fast(mreg - mn);
            mreg = mn; lsum *= sc_;
            if (hi == 0) lsum_lds[w][l31] = sc_;
            asm volatile("s_waitcnt lgkmcnt(0)" ::: "memory");
            #pragma unroll
            for (int r = 0; r < 16; r++) {
                int crow = (r & 3) + ((r >> 2) << 3) + (hi << 2);
                float srw = lsum_lds[w][crow];
                o0[r] *= srw; o1[r] *= srw;
            }
        }

        #pragma unroll
        for (int r = 0; r < 16; r++) s[r] = exp2_fast(s[r] - mreg);

        float a0 = s[0] + s[1],   a1 = s[2] + s[3];
        float a2 = s[4] + s[5],   a3 = s[6] + s[7];
        float a4 = s[8] + s[9],   a5 = s[10] + s[11];
        float a6 = s[12] + s[13], a7 = s[14] + s[15];
        float rsum = ((a0 + a1) + (a2 + a3)) + ((a4 + a5) + (a6 + a7));
        float2 rh = xhalves(rsum);
        lsum += rh.x + rh.y;

        unsigned c0 = cvt_pk_bf16(s[0], s[1]);
        unsigned c1 = cvt_pk_bf16(s[2], s[3]);
        unsigned c2 = cvt_pk_bf16(s[4], s[5]);
        unsigned c3 = cvt_pk_bf16(s[6], s[7]);
        unsigned c4 = cvt_pk_bf16(s[8], s[9]);
        unsigned c5 = cvt_pk_bf16(s[10], s[11]);
        unsigned c6 = cvt_pk_bf16(s[12], s[13]);
        unsigned c7 = cvt_pk_bf16(s[14], s[15]);
        plswap(c0, c2);
        plswap(c1, c3);
        plswap(c4, c6);
        plswap(c5, c7);

        union U { unsigned u[4]; bf16x8 v; };
        U f0, f1;
        f0.u[0] = c0; f0.u[1] = c1; f0.u[2] = c2; f0.u[3] = c3;
        f1.u[0] = c4; f1.u[1] = c5; f1.u[2] = c6; f1.u[3] = c7;

        __builtin_amdgcn_s_setprio(1);
        o0 = __builtin_amdgcn_mfma_f32_32x32x16_bf16(f0.v, vf00, o0, 0, 0, 0);
        o0 = __builtin_amdgcn_mfma_f32_32x32x16_bf16(f1.v, vf01, o0, 0, 0, 0);
        o1 = __builtin_amdgcn_mfma_f32_32x32x16_bf16(f0.v, vf10, o1, 0, 0, 0);
        o1 = __builtin_amdgcn_mfma_f32_32x32x16_bf16(f1.v, vf11, o1, 0, 0, 0);
        __builtin_amdgcn_s_setprio(0);
    };

    // ---- pipeline prologue ----
    LOADST(0);
    WRITEST(0);
    LOADST(64);
    asm volatile("s_waitcnt lgkmcnt(0)" ::: "memory");
    __builtin_amdgcn_s_barrier();
    asm volatile("" ::: "memory");

    int cur = 0;
    for (int t = 0; t < 16; t++) {
        if (t < 15) {
            WRITEST(cur ^ 1);
            if (t < 14) LOADST((t + 2) * 64);
        }
        subtile(cur, 0);
        subtile(cur, 1);
        if (t < 15) {
            asm volatile("" ::: "memory");
            asm volatile("s_waitcnt lgkmcnt(0)" ::: "memory");
            __builtin_amdgcn_s_barrier();
            asm volatile("" ::: "memory");
        }
        cur ^= 1;
    }
#undef LOADST
#undef WRITEST

    if (hi == 0) lsum_lds[w][l31] = lsum;
    asm volatile("s_waitcnt lgkmcnt(0)" ::: "memory");
    #pragma unroll
    for (int r = 0; r < 16; r++) {
        int crow = (r & 3) + ((r >> 2) << 3) + (hi << 2);
        float inv = rcp_fast(lsum_lds[w][crow]);
        float* op = out + ((size_t)(bb * S_ + qbase + crow)) * D_ + hh * DH_ + l31;
        op[0]  = o0[r] * inv;
        op[32] = o1[r] * inv;
    }
}

// ---------------------------------------------------------------------------
// Kernel 3 (v2): y = LN(2*out + q) * gamma + beta; 192 thr/row, f32x4 loads.
// ---------------------------------------------------------------------------
__global__ __launch_bounds__(192) void ln_kernel(
    const float* __restrict__ qin, const float* __restrict__ gamma,
    const float* __restrict__ beta, float* __restrict__ out)
{
    int row = blockIdx.x;
    int tid = threadIdx.x;
    size_t base = (size_t)row * D_ + tid * 4;

    f32x4 o  = *(const f32x4*)(out + base);
    f32x4 qv = *(const f32x4*)(qin + base);
    f32x4 x;
    float sum = 0.f, sq = 0.f;
    #pragma unroll
    for (int i = 0; i < 4; i++) {
        x[i] = 2.f * o[i] + qv[i];
        sum += x[i];
        sq  += x[i] * x[i];
    }
    #pragma unroll
    for (int msk = 1; msk < 64; msk <<= 1) {
        sum += __shfl_xor(sum, msk);
        sq  += __shfl_xor(sq, msk);
    }
    __shared__ float s1[3], s2[3];
    if ((tid & 63) == 0) { s1[tid >> 6] = sum; s2[tid >> 6] = sq; }
    __syncthreads();
    sum = s1[0] + s1[1] + s1[2];
    sq  = s2[0] + s2[1] + s2[2];
    float mu   = sum * (1.f / D_);
    float var  = sq * (1.f / D_) - mu * mu;
    float rstd = rsqrtf(var + 1e-5f);
    f32x4 g = *(const f32x4*)(gamma + tid * 4);
    f32x4 b = *(const f32x4*)(beta + tid * 4);
    f32x4 y;
    #pragma unroll
    for (int i = 0; i < 4; i++)
        y[i] = (x[i] - mu) * rstd * g[i] + b[i];
    *(f32x4*)(out + base) = y;
}

// ---------------------------------------------------------------------------
extern "C" void kernel_launch(void* const* d_in, const int* in_sizes, int n_in,
                              void* d_out, int out_size, void* d_ws, size_t ws_size,
                              hipStream_t stream)
{
    const float* q     = (const float*)d_in[0];
    const float* k     = (const float*)d_in[1];
    const float* v     = (const float*)d_in[2];
    const float* W     = (const float*)d_in[3];
    const float* gamma = (const float*)d_in[4];
    const float* beta  = (const float*)d_in[5];

    size_t per = (size_t)B_ * H_ * S_ * DH_;
    short* q1  = (short*)d_ws;
    short* k1  = q1 + per;
    short* v1t = k1 + per;
    float* out = (float*)d_out;

    proj_kernel<<<dim3(1152), dim3(256), 0, stream>>>(q, k, v, W, q1, k1, v1t);
    attn_kernel<<<dim3(768), dim3(256), 0, stream>>>(q1, k1, v1t, out);
    ln_kernel<<<dim3(B_ * S_), dim3(192), 0, stream>>>(q, gamma, beta, out);
}

// Round 9
// 128.021 us; speedup vs baseline: 1.8189x; 1.0168x over previous
//
#include <hip/hip_runtime.h>
#include <hip/hip_bf16.h>

// Problem constants (B,S,D,H fixed by setup_inputs)
#define B_  8
#define S_  1024
#define D_  768
#define H_  12
#define DH_ 64

typedef __attribute__((ext_vector_type(8))) short bf16x8;
typedef __attribute__((ext_vector_type(4))) float f32x4;
typedef __attribute__((ext_vector_type(16))) float f32x16;

__device__ inline short f2bf(float f) {
    unsigned u = __builtin_bit_cast(unsigned, f);
    u = (u + 0x7fffu + ((u >> 16) & 1u)) >> 16;   // RNE
    return (short)u;
}
__device__ inline float exp2_fast(float x) {
    float r; asm("v_exp_f32 %0, %1" : "=v"(r) : "v"(x)); return r;
}
__device__ inline unsigned cvt_pk_bf16(float lo, float hi) {
    unsigned r; asm("v_cvt_pk_bf16_f32 %0, %1, %2" : "=v"(r) : "v"(lo), "v"(hi)); return r;
}
__device__ inline float rcp_fast(float x) {
    float r; asm("v_rcp_f32 %0, %1" : "=v"(r) : "v"(x)); return r;
}
// Builtin permlane32_swap (compiler inserts the VALU->permlane hazard waits).
__device__ inline void plswap(unsigned& a, unsigned& b) {
    auto r = __builtin_amdgcn_permlane32_swap(a, b, false, false);
    a = r[0]; b = r[1];
}
__device__ inline float2 xhalves(float x) {
    unsigned u = __builtin_bit_cast(unsigned, x);
    auto r = __builtin_amdgcn_permlane32_swap(u, u, false, false);
    return make_float2(__builtin_bit_cast(float, r[0]),
                       __builtin_bit_cast(float, r[1]));
}
// Async global->LDS, 16B per lane. LDS dest is wave-uniform base + lane*16;
// global src is per-lane (swizzle lives in the source address — rule 21).
__device__ inline void gl_lds16(const float* gsrc, char* ldst) {
    __builtin_amdgcn_global_load_lds(
        (const __attribute__((address_space(1))) unsigned int*)gsrc,
        (__attribute__((address_space(3))) unsigned int*)ldst,
        16, 0, 0);
}

// ---------------------------------------------------------------------------
// Kernel 1 (v4): Y = relu(X @ W^T), X in {q,k,v} stacked along M (24576 rows).
// 128x128 tile, BK=32. Staging via global_load_lds of the RAW f32 data
// (no VGPR round-trip, no ds_writes); f32->bf16 conversion fused into the
// fragment read (2x ds_read_b128 + 4x cvt_pk per fragment).
// LDS: A 128x32 f32 (16KB) + B 16KB = 32KB single buffer -> 5 blocks/CU.
// Swizzle: LDS[r][slot s] holds global chunk s^(r&7) (inverse-swizzled
// per-lane source); frag reads use slot (2g+j)^(r&7) -> exactly 8 lanes/bank
// (wave64 b128 floor, conflict-free).
// m97 2-barrier loop: barrier; issue 8 gl_lds16/wave; vmcnt(0); barrier;
// read+cvt+MFMA.
// ---------------------------------------------------------------------------
__global__ __launch_bounds__(256) void proj_kernel(
    const float* __restrict__ q, const float* __restrict__ k,
    const float* __restrict__ v, const float* __restrict__ W,
    short* __restrict__ q1, short* __restrict__ k1, short* __restrict__ v1t)
{
    __shared__ __align__(16) char lds_raw[32768];   // A 16K | B 16K; epilogue overlay

    int p  = blockIdx.x;
    int L  = (p & 7) * 144 + (p >> 3);   // XCD-chunked swizzle (1152 = 8*144)
    int mt = L / 6, nt = L % 6;
    int t  = mt >> 6;                    // 0=q,1=k,2=v
    int m0 = (mt & 63) << 7;
    int n0 = nt << 7;
    const float* X = (t == 0) ? q : (t == 1) ? k : v;

    int tid = threadIdx.x, lane = tid & 63, w = tid >> 6;
    int wr = w >> 1, wc = w & 1;
    int l15 = lane & 15, g = lane >> 4;

    // per-lane global sources for the 4 staging instructions of this wave.
    // inst i: lane l covers LDS row r = w*32 + i*8 + (l>>3), slot s = l&7;
    // LDS[r][s] must hold chunk s^(r&7) -> source col = (s^(r&7))*4 f32.
    const float* srcA[4];
    const float* srcB[4];
    #pragma unroll
    for (int i = 0; i < 4; i++) {
        int r  = w * 32 + i * 8 + (lane >> 3);
        int sp = (lane & 7) ^ (r & 7);
        srcA[i] = X + (size_t)(m0 + r) * D_ + sp * 4;
        srcB[i] = W + (size_t)(n0 + r) * D_ + sp * 4;
    }

    f32x4 acc[4][4];
    #pragma unroll
    for (int m = 0; m < 4; m++)
        #pragma unroll
        for (int n = 0; n < 4; n++) acc[m][n] = (f32x4){0.f, 0.f, 0.f, 0.f};

    for (int kb = 0; kb < 24; ++kb) {
        __builtin_amdgcn_s_barrier();        // all waves done reading prev step
        asm volatile("" ::: "memory");
        #pragma unroll
        for (int i = 0; i < 4; i++) {
            gl_lds16(srcA[i] + kb * 32, lds_raw + w * 4096 + i * 1024);
            gl_lds16(srcB[i] + kb * 32, lds_raw + 16384 + w * 4096 + i * 1024);
        }
        asm volatile("s_waitcnt vmcnt(0)" ::: "memory");
        __builtin_amdgcn_s_barrier();        // tile ready
        asm volatile("" ::: "memory");

        bf16x8 af[4], bfv[4];
        #pragma unroll
        for (int m = 0; m < 4; m++) {
            int r = wr * 64 + m * 16 + l15;
            const char* rp = lds_raw + r * 128;
            f32x4 lo = *(const f32x4*)(rp + (((2 * g)     ^ (r & 7)) << 4));
            f32x4 hi = *(const f32x4*)(rp + (((2 * g + 1) ^ (r & 7)) << 4));
            uint4 pk;
            pk.x = cvt_pk_bf16(lo[0], lo[1]); pk.y = cvt_pk_bf16(lo[2], lo[3]);
            pk.z = cvt_pk_bf16(hi[0], hi[1]); pk.w = cvt_pk_bf16(hi[2], hi[3]);
            af[m] = __builtin_bit_cast(bf16x8, pk);
        }
        #pragma unroll
        for (int n = 0; n < 4; n++) {
            int r = wc * 64 + n * 16 + l15;
            const char* rp = lds_raw + 16384 + r * 128;
            f32x4 lo = *(const f32x4*)(rp + (((2 * g)     ^ (r & 7)) << 4));
            f32x4 hi = *(const f32x4*)(rp + (((2 * g + 1) ^ (r & 7)) << 4));
            uint4 pk;
            pk.x = cvt_pk_bf16(lo[0], lo[1]); pk.y = cvt_pk_bf16(lo[2], lo[3]);
            pk.z = cvt_pk_bf16(hi[0], hi[1]); pk.w = cvt_pk_bf16(hi[2], hi[3]);
            bfv[n] = __builtin_bit_cast(bf16x8, pk);
        }
        __builtin_amdgcn_s_setprio(1);
        #pragma unroll
        for (int m = 0; m < 4; m++)
            #pragma unroll
            for (int n = 0; n < 4; n++)
                acc[m][n] = __builtin_amdgcn_mfma_f32_16x16x32_bf16(
                    af[m], bfv[n], acc[m][n], 0, 0, 0);
        __builtin_amdgcn_s_setprio(0);
    }

    // Epilogue: relu(+scale) -> bf16 -> swizzled-LDS transpose -> b128 stores.
    // Ts: 128 rows x 16 slots of 16B; byte = r*256 + ((slot^(r&15))<<4) + (c&7)*2
    __syncthreads();
    const float sc1 = (t == 1) ? 0.18033688011112793f : 1.0f;  // 1/8*log2(e)
    #pragma unroll
    for (int m = 0; m < 4; m++) {
        int rb = wr * 64 + m * 16 + (g << 2);
        #pragma unroll
        for (int n = 0; n < 4; n++) {
            int cb = wc * 64 + n * 16 + l15;
            #pragma unroll
            for (int r = 0; r < 4; r++) {
                short vv = f2bf(fmaxf(acc[m][n][r], 0.f) * sc1);
                int rr = (t == 2) ? cb : rb + r;     // v: store transposed
                int cc = (t == 2) ? rb + r : cb;
                *(short*)(lds_raw + rr * 256 + (((cc >> 3) ^ (rr & 15)) << 4)
                          + ((cc & 7) << 1)) = vv;
            }
        }
    }
    __syncthreads();
    int row = tid >> 1;
    int c0  = (tid & 1) << 6;
    bf16x8 ov[8];
    #pragma unroll
    for (int j = 0; j < 8; j++)
        ov[j] = *(const bf16x8*)(lds_raw + row * 256 +
                 ((((c0 >> 3) + j) ^ (row & 15)) << 4));
    if (t == 2) {
        int gc = n0 + row;
        int hh2 = gc >> 6, dh = gc & 63;
        int bb = m0 >> 10, s0 = m0 & 1023;
        short* dst = v1t + (((size_t)bb * H_ + hh2) * DH_ + dh) * S_ + s0 + c0;
        #pragma unroll
        for (int j = 0; j < 8; j++) *(bf16x8*)(dst + j * 8) = ov[j];
    } else {
        int m = m0 + row;
        int bb = m >> 10, ss = m & 1023;
        int hh2 = (n0 >> 6) + (tid & 1);
        short* dst = (t ? k1 : q1) + (((size_t)bb * H_ + hh2) * S_ + ss) * DH_;
        #pragma unroll
        for (int j = 0; j < 8; j++) *(bf16x8*)(dst + j * 8) = ov[j];
    }
}

// ---------------------------------------------------------------------------
// Kernel 2 (v5): flash attention, swapped-QK^T 32x32x16, block-cooperative
// LDS-staged K/V (unchanged from round 6 -- passing, fast).
// ---------------------------------------------------------------------------
__global__ __launch_bounds__(256, 3) void attn_kernel(
    const short* __restrict__ q1, const short* __restrict__ k1,
    const short* __restrict__ v1t, float* __restrict__ out)
{
    __shared__ short Klds[2][4096];   // [buf][64 kv rows][64 dh], swizzled
    __shared__ short Vlds[2][4096];   // [buf][64 dh rows][64 kv], swizzled
    __shared__ float lsum_lds[4][32];

    int d    = blockIdx.x;                       // 0..767
    int head = (d & 7) + ((d >> 6) << 3);        // same head -> same XCD
    int qi   = (d >> 3) & 7;
    int bb   = head / H_, hh = head % H_;

    int tid = threadIdx.x, lane = tid & 63, w = tid >> 6;
    int l31 = lane & 31, hi = lane >> 5;
    int qbase = (qi * 4 + w) * 32;

    const short* Qp = q1  + (size_t)head * S_ * DH_;
    const short* Kp = k1  + (size_t)head * S_ * DH_;
    const short* Vp = v1t + (size_t)head * DH_ * S_;

    // staging geometry: thread -> (row r, 16B slot c / c+4)
    int sr = tid >> 2, sc = tid & 3;
    int swz0 = sr * 128 + ((sc       ^ (sr & 7)) << 4);
    int swz1 = sr * 128 + (((sc + 4) ^ (sr & 7)) << 4);

    bf16x8 stK0, stK1, stV0, stV1;

#define LOADST(kvb) do { \
        const short* _kg = Kp + (size_t)((kvb) + sr) * DH_; \
        const short* _vg = Vp + (size_t)sr * S_ + (kvb); \
        stK0 = *(const bf16x8*)(_kg + sc * 8); \
        stK1 = *(const bf16x8*)(_kg + (sc + 4) * 8); \
        stV0 = *(const bf16x8*)(_vg + sc * 8); \
        stV1 = *(const bf16x8*)(_vg + (sc + 4) * 8); \
    } while (0)
#define WRITEST(buf) do { \
        char* _kb = (char*)&Klds[buf][0]; \
        char* _vb = (char*)&Vlds[buf][0]; \
        *(bf16x8*)(_kb + swz0) = stK0; \
        *(bf16x8*)(_kb + swz1) = stK1; \
        *(bf16x8*)(_vb + swz0) = stV0; \
        *(bf16x8*)(_vb + swz1) = stV1; \
    } while (0)

    bf16x8 qf[4];
    #pragma unroll
    for (int kb = 0; kb < 4; kb++)
        qf[kb] = *(const bf16x8*)(Qp + (size_t)(qbase + l31) * DH_ + kb * 16 + hi * 8);

    f32x16 o0, o1;
    #pragma unroll
    for (int r = 0; r < 16; r++) { o0[r] = 0.f; o1[r] = 0.f; }
    float mreg = -1e30f, lsum = 0.f;

    int xk = l31 & 7;   // row-XOR for fragment reads

    auto subtile = [&](int cur, int j) {
        const char* Kt = (const char*)&Klds[cur][0];
        const char* Vt = (const char*)&Vlds[cur][0];
        int rK = (32 * j + l31) * 128;
        bf16x8 kf0 = *(const bf16x8*)(Kt + rK + (((0 + hi) ^ xk) << 4));
        bf16x8 kf1 = *(const bf16x8*)(Kt + rK + (((2 + hi) ^ xk) << 4));
        bf16x8 kf2 = *(const bf16x8*)(Kt + rK + (((4 + hi) ^ xk) << 4));
        bf16x8 kf3 = *(const bf16x8*)(Kt + rK + (((6 + hi) ^ xk) << 4));
        int rV0 = l31 * 128, rV1 = (32 + l31) * 128;
        int s0 = ((4 * j + hi) ^ xk) << 4, s1 = ((4 * j + 2 + hi) ^ xk) << 4;
        bf16x8 vf00 = *(const bf16x8*)(Vt + rV0 + s0);
        bf16x8 vf01 = *(const bf16x8*)(Vt + rV0 + s1);
        bf16x8 vf10 = *(const bf16x8*)(Vt + rV1 + s0);
        bf16x8 vf11 = *(const bf16x8*)(Vt + rV1 + s1);

        f32x16 s;
        #pragma unroll
        for (int r = 0; r < 16; r++) s[r] = 0.f;
        __builtin_amdgcn_s_setprio(1);
        s = __builtin_amdgcn_mfma_f32_32x32x16_bf16(kf0, qf[0], s, 0, 0, 0);
        s = __builtin_amdgcn_mfma_f32_32x32x16_bf16(kf1, qf[1], s, 0, 0, 0);
        s = __builtin_amdgcn_mfma_f32_32x32x16_bf16(kf2, qf[2], s, 0, 0, 0);
        s = __builtin_amdgcn_mfma_f32_32x32x16_bf16(kf3, qf[3], s, 0, 0, 0);
        __builtin_amdgcn_s_setprio(0);

        float t0 = fmaxf(s[0], s[1]),   t1 = fmaxf(s[2], s[3]);
        float t2 = fmaxf(s[4], s[5]),   t3 = fmaxf(s[6], s[7]);
        float t4 = fmaxf(s[8], s[9]),   t5 = fmaxf(s[10], s[11]);
        float t6 = fmaxf(s[12], s[13]), t7 = fmaxf(s[14], s[15]);
        float u0 = fmaxf(t0, t1), u1 = fmaxf(t2, t3);
        float u2 = fmaxf(t4, t5), u3 = fmaxf(t6, t7);
        float pmax = fmaxf(fmaxf(u0, u1), fmaxf(u2, u3));
        float2 ph = xhalves(pmax);
        pmax = fmaxf(ph.x, ph.y);

        if (!__all(pmax <= mreg + 8.f)) {       // defer-max (T13), log2 domain
            float mn = fmaxf(mreg, pmax);
            float sc_ = exp2_fast(mreg - mn);
            mreg = mn; lsum *= sc_;
            if (hi == 0) lsum_lds[w][l31] = sc_;
            asm volatile("s_waitcnt lgkmcnt(0)" ::: "memory");
            #pragma unroll
            for (int r = 0; r < 16; r++) {
                int crow = (r & 3) + ((r >> 2) << 3) + (hi << 2);
                float srw = lsum_lds[w][crow];
                o0[r] *= srw; o1[r] *= srw;
            }
        }

        #pragma unroll
        for (int r = 0; r < 16; r++) s[r] = exp2_fast(s[r] - mreg);

        float a0 = s[0] + s[1],   a1 = s[2] + s[3];
        float a2 = s[4] + s[5],   a3 = s[6] + s[7];
        float a4 = s[8] + s[9],   a5 = s[10] + s[11];
        float a6 = s[12] + s[13], a7 = s[14] + s[15];
        float rsum = ((a0 + a1) + (a2 + a3)) + ((a4 + a5) + (a6 + a7));
        float2 rh = xhalves(rsum);
        lsum += rh.x + rh.y;

        unsigned c0 = cvt_pk_bf16(s[0], s[1]);
        unsigned c1 = cvt_pk_bf16(s[2], s[3]);
        unsigned c2 = cvt_pk_bf16(s[4], s[5]);
        unsigned c3 = cvt_pk_bf16(s[6], s[7]);
        unsigned c4 = cvt_pk_bf16(s[8], s[9]);
        unsigned c5 = cvt_pk_bf16(s[10], s[11]);
        unsigned c6 = cvt_pk_bf16(s[12], s[13]);
        unsigned c7 = cvt_pk_bf16(s[14], s[15]);
        plswap(c0, c2);
        plswap(c1, c3);
        plswap(c4, c6);
        plswap(c5, c7);

        union U { unsigned u[4]; bf16x8 v; };
        U f0, f1;
        f0.u[0] = c0; f0.u[1] = c1; f0.u[2] = c2; f0.u[3] = c3;
        f1.u[0] = c4; f1.u[1] = c5; f1.u[2] = c6; f1.u[3] = c7;

        __builtin_amdgcn_s_setprio(1);
        o0 = __builtin_amdgcn_mfma_f32_32x32x16_bf16(f0.v, vf00, o0, 0, 0, 0);
        o0 = __builtin_amdgcn_mfma_f32_32x32x16_bf16(f1.v, vf01, o0, 0, 0, 0);
        o1 = __builtin_amdgcn_mfma_f32_32x32x16_bf16(f0.v, vf10, o1, 0, 0, 0);
        o1 = __builtin_amdgcn_mfma_f32_32x32x16_bf16(f1.v, vf11, o1, 0, 0, 0);
        __builtin_amdgcn_s_setprio(0);
    };

    // ---- pipeline prologue ----
    LOADST(0);
    WRITEST(0);
    LOADST(64);
    asm volatile("s_waitcnt lgkmcnt(0)" ::: "memory");
    __builtin_amdgcn_s_barrier();
    asm volatile("" ::: "memory");

    int cur = 0;
    for (int t = 0; t < 16; t++) {
        if (t < 15) {
            WRITEST(cur ^ 1);
            if (t < 14) LOADST((t + 2) * 64);
        }
        subtile(cur, 0);
        subtile(cur, 1);
        if (t < 15) {
            asm volatile("" ::: "memory");
            asm volatile("s_waitcnt lgkmcnt(0)" ::: "memory");
            __builtin_amdgcn_s_barrier();
            asm volatile("" ::: "memory");
        }
        cur ^= 1;
    }
#undef LOADST
#undef WRITEST

    if (hi == 0) lsum_lds[w][l31] = lsum;
    asm volatile("s_waitcnt lgkmcnt(0)" ::: "memory");
    #pragma unroll
    for (int r = 0; r < 16; r++) {
        int crow = (r & 3) + ((r >> 2) << 3) + (hi << 2);
        float inv = rcp_fast(lsum_lds[w][crow]);
        float* op = out + ((size_t)(bb * S_ + qbase + crow)) * D_ + hh * DH_ + l31;
        op[0]  = o0[r] * inv;
        op[32] = o1[r] * inv;
    }
}

// ---------------------------------------------------------------------------
// Kernel 3 (v2): y = LN(2*out + q) * gamma + beta; 192 thr/row, f32x4 loads.
// ---------------------------------------------------------------------------
__global__ __launch_bounds__(192) void ln_kernel(
    const float* __restrict__ qin, const float* __restrict__ gamma,
    const float* __restrict__ beta, float* __restrict__ out)
{
    int row = blockIdx.x;
    int tid = threadIdx.x;
    size_t base = (size_t)row * D_ + tid * 4;

    f32x4 o  = *(const f32x4*)(out + base);
    f32x4 qv = *(const f32x4*)(qin + base);
    f32x4 x;
    float sum = 0.f, sq = 0.f;
    #pragma unroll
    for (int i = 0; i < 4; i++) {
        x[i] = 2.f * o[i] + qv[i];
        sum += x[i];
        sq  += x[i] * x[i];
    }
    #pragma unroll
    for (int msk = 1; msk < 64; msk <<= 1) {
        sum += __shfl_xor(sum, msk);
        sq  += __shfl_xor(sq, msk);
    }
    __shared__ float s1[3], s2[3];
    if ((tid & 63) == 0) { s1[tid >> 6] = sum; s2[tid >> 6] = sq; }
    __syncthreads();
    sum = s1[0] + s1[1] + s1[2];
    sq  = s2[0] + s2[1] + s2[2];
    float mu   = sum * (1.f / D_);
    float var  = sq * (1.f / D_) - mu * mu;
    float rstd = rsqrtf(var + 1e-5f);
    f32x4 g = *(const f32x4*)(gamma + tid * 4);
    f32x4 b = *(const f32x4*)(beta + tid * 4);
    f32x4 y;
    #pragma unroll
    for (int i = 0; i < 4; i++)
        y[i] = (x[i] - mu) * rstd * g[i] + b[i];
    *(f32x4*)(out + base) = y;
}

// ---------------------------------------------------------------------------
extern "C" void kernel_launch(void* const* d_in, const int* in_sizes, int n_in,
                              void* d_out, int out_size, void* d_ws, size_t ws_size,
                              hipStream_t stream)
{
    const float* q     = (const float*)d_in[0];
    const float* k     = (const float*)d_in[1];
    const float* v     = (const float*)d_in[2];
    const float* W     = (const float*)d_in[3];
    const float* gamma = (const float*)d_in[4];
    const float* beta  = (const float*)d_in[5];

    size_t per = (size_t)B_ * H_ * S_ * DH_;
    short* q1  = (short*)d_ws;
    short* k1  = q1 + per;
    short* v1t = k1 + per;
    float* out = (float*)d_out;

    proj_kernel<<<dim3(1152), dim3(256), 0, stream>>>(q, k, v, W, q1, k1, v1t);
    attn_kernel<<<dim3(768), dim3(256), 0, stream>>>(q1, k1, v1t, out);
    ln_kernel<<<dim3(B_ * S_), dim3(192), 0, stream>>>(q, gamma, beta, out);
}

// Round 10
// 117.920 us; speedup vs baseline: 1.9747x; 1.0857x over previous
//
#include <hip/hip_runtime.h>
#include <hip/hip_bf16.h>

// Problem constants (B,S,D,H fixed by setup_inputs)
#define B_  8
#define S_  1024
#define D_  768
#define H_  12
#define DH_ 64

typedef __attribute__((ext_vector_type(8))) short bf16x8;
typedef __attribute__((ext_vector_type(4))) float f32x4;
typedef __attribute__((ext_vector_type(16))) float f32x16;

__device__ inline short f2bf(float f) {
    unsigned u = __builtin_bit_cast(unsigned, f);
    u = (u + 0x7fffu + ((u >> 16) & 1u)) >> 16;   // RNE
    return (short)u;
}
__device__ inline float exp2_fast(float x) {
    float r; asm("v_exp_f32 %0, %1" : "=v"(r) : "v"(x)); return r;
}
__device__ inline unsigned cvt_pk_bf16(float lo, float hi) {
    unsigned r; asm("v_cvt_pk_bf16_f32 %0, %1, %2" : "=v"(r) : "v"(lo), "v"(hi)); return r;
}
__device__ inline float rcp_fast(float x) {
    float r; asm("v_rcp_f32 %0, %1" : "=v"(r) : "v"(x)); return r;
}
__device__ inline void plswap(unsigned& a, unsigned& b) {
    auto r = __builtin_amdgcn_permlane32_swap(a, b, false, false);
    a = r[0]; b = r[1];
}
__device__ inline float2 xhalves(float x) {
    unsigned u = __builtin_bit_cast(unsigned, x);
    auto r = __builtin_amdgcn_permlane32_swap(u, u, false, false);
    return make_float2(__builtin_bit_cast(float, r[0]),
                       __builtin_bit_cast(float, r[1]));
}
// Async global->LDS, 16B/lane. LDS dest = wave-uniform base + lane*16;
// swizzle lives in the per-lane GLOBAL source address (rule 21).
__device__ inline void gl_lds16(const void* gsrc, char* ldst) {
    __builtin_amdgcn_global_load_lds(
        (const __attribute__((address_space(1))) unsigned int*)gsrc,
        (__attribute__((address_space(3))) unsigned int*)ldst,
        16, 0, 0);
}

// ---------------------------------------------------------------------------
// Kernel 0: W f32 -> bf16 (one-time; makes proj's B-stream half-width and
// gl_lds-stageable). 589824 elems, 8 per thread.
// ---------------------------------------------------------------------------
__global__ __launch_bounds__(256) void convw_kernel(
    const float* __restrict__ W, short* __restrict__ Wb)
{
    int i = (blockIdx.x * 256 + threadIdx.x) * 8;
    f32x4 a = *(const f32x4*)(W + i);
    f32x4 b = *(const f32x4*)(W + i + 4);
    uint4 pk;
    pk.x = cvt_pk_bf16(a[0], a[1]); pk.y = cvt_pk_bf16(a[2], a[3]);
    pk.z = cvt_pk_bf16(b[0], b[1]); pk.w = cvt_pk_bf16(b[2], b[3]);
    *(uint4*)(Wb + i) = pk;
}

// ---------------------------------------------------------------------------
// Kernel 1 (v6): Y = relu(X @ W^T). Traffic-restructured:
// - block = 64 m-rows x 384 n-cols (BN=384 -> A-panels read 2x not 6x)
// - 512 threads / 8 waves; wave w owns cols [w*48, w*48+48) (4x3 frags)
// - B operand = pre-converted Wb (bf16) staged via gl_lds (24KB/step)
// - A operand = X f32 staged via gl_lds (8KB/step), cvt_pk fused in frag read
// - double-buffered, COUNTED vmcnt(4) per step (T4: never drain to 0)
// - LDS exactly 64KB -> 2 blocks/CU; XCD swizzle pairs the 2 n-blocks of
//   each m-panel on one XCD (A panel shared via its L2)
// ---------------------------------------------------------------------------
__global__ __launch_bounds__(512) void proj_kernel(
    const float* __restrict__ q, const float* __restrict__ k,
    const float* __restrict__ v, const short* __restrict__ Wb,
    short* __restrict__ q1, short* __restrict__ k1, short* __restrict__ v1t)
{
    __shared__ __align__(16) char lds[65536];
    // X bufs at 0, 8192      : [64 rows][8 chunks16B], slot = c ^ (row&7)
    // W bufs at 16384, 40960 : [384 rows][4 chunks16B], slot = c ^ ((row>>1)&3)

    int p  = blockIdx.x;
    int L  = (p & 7) * 96 + (p >> 3);        // 768 blocks = 8 XCD x 96
    int mt = L >> 1, nb = L & 1;
    int t  = mt >> 7;                        // 128 m-blocks per input
    int m0 = (mt & 127) << 6;
    int n0 = nb * 384;
    const float* X = (t == 0) ? q : (t == 1) ? k : v;

    int tid = threadIdx.x, lane = tid & 63, w = tid >> 6;   // w 0..7
    int l15 = lane & 15, g = lane >> 4;

    // staging source addresses (per-lane, pre-swizzled)
    int xrow = w * 8 + (lane >> 3), xc = lane & 7;
    const float* xsrc = X + (size_t)(m0 + xrow) * D_ + ((xc ^ (xrow & 7)) << 2);
    char* xdst = lds + w * 1024;
    int wrow0 = w * 48 + (lane >> 2), wc = lane & 3;
    int wrow1 = wrow0 + 16, wrow2 = wrow0 + 32;
    const short* wsrc0 = Wb + (size_t)(n0 + wrow0) * D_ + ((wc ^ ((wrow0 >> 1) & 3)) << 3);
    const short* wsrc1 = Wb + (size_t)(n0 + wrow1) * D_ + ((wc ^ ((wrow1 >> 1) & 3)) << 3);
    const short* wsrc2 = Wb + (size_t)(n0 + wrow2) * D_ + ((wc ^ ((wrow2 >> 1) & 3)) << 3);
    char* wdst = lds + 16384 + w * 3072;

#define ISSUE(s_, b_) do { int _ko = (s_) * 32; \
        gl_lds16(xsrc + _ko, xdst + (b_) * 8192); \
        gl_lds16(wsrc0 + _ko, wdst + (b_) * 24576); \
        gl_lds16(wsrc1 + _ko, wdst + (b_) * 24576 + 1024); \
        gl_lds16(wsrc2 + _ko, wdst + (b_) * 24576 + 2048); \
    } while (0)

    f32x4 acc[4][3];
    #pragma unroll
    for (int m = 0; m < 4; m++)
        #pragma unroll
        for (int n = 0; n < 3; n++) acc[m][n] = (f32x4){0.f, 0.f, 0.f, 0.f};

    ISSUE(0, 0);
    for (int s = 0; s < 24; ++s) {
        __builtin_amdgcn_s_barrier();            // reads of target buf done
        asm volatile("" ::: "memory");
        if (s + 1 < 24) {
            ISSUE(s + 1, (s + 1) & 1);
            asm volatile("s_waitcnt vmcnt(4)" ::: "memory");   // step-s landed
        } else {
            asm volatile("s_waitcnt vmcnt(0)" ::: "memory");
        }
        __builtin_amdgcn_s_barrier();            // all waves' loads landed
        asm volatile("" ::: "memory");

        const char* Xb = lds + (s & 1) * 8192;
        const char* Wp = lds + 16384 + (s & 1) * 24576;
        bf16x8 af[4];
        #pragma unroll
        for (int m = 0; m < 4; m++) {
            int r = m * 16 + l15;
            const char* rp = Xb + r * 128;
            f32x4 lo = *(const f32x4*)(rp + (((2 * g)     ^ (r & 7)) << 4));
            f32x4 hi = *(const f32x4*)(rp + (((2 * g + 1) ^ (r & 7)) << 4));
            uint4 pk;
            pk.x = cvt_pk_bf16(lo[0], lo[1]); pk.y = cvt_pk_bf16(lo[2], lo[3]);
            pk.z = cvt_pk_bf16(hi[0], hi[1]); pk.w = cvt_pk_bf16(hi[2], hi[3]);
            af[m] = __builtin_bit_cast(bf16x8, pk);
        }
        bf16x8 bfv[3];
        #pragma unroll
        for (int n = 0; n < 3; n++) {
            int r = w * 48 + n * 16 + l15;
            bfv[n] = *(const bf16x8*)(Wp + r * 64 + ((g ^ ((r >> 1) & 3)) << 4));
        }
        __builtin_amdgcn_s_setprio(1);
        #pragma unroll
        for (int m = 0; m < 4; m++)
            #pragma unroll
            for (int n = 0; n < 3; n++)
                acc[m][n] = __builtin_amdgcn_mfma_f32_16x16x32_bf16(
                    af[m], bfv[n], acc[m][n], 0, 0, 0);
        __builtin_amdgcn_s_setprio(0);
    }
#undef ISSUE

    // Epilogue: relu(+scale) -> bf16 -> swizzled LDS transpose -> b128 stores.
    // q/k overlay: [64 rows][48 chunks16B], slot = ch ^ (row&7)  (48KB)
    // v overlay  : [384 rows][8 chunks16B], slot = ch ^ (row&7)  (48KB)
    __syncthreads();
    const float sc1 = (t == 1) ? 0.18033688011112793f : 1.0f;  // 1/8*log2(e)
    #pragma unroll
    for (int m = 0; m < 4; m++)
        #pragma unroll
        for (int n = 0; n < 3; n++)
            #pragma unroll
            for (int r = 0; r < 4; r++) {
                int row = m * 16 + g * 4 + r;
                int col = w * 48 + n * 16 + l15;
                short vv = f2bf(fmaxf(acc[m][n][r], 0.f) * sc1);
                if (t == 2)   // v stored transposed: Ts[col 0..383][row 0..63]
                    *(short*)(lds + col * 128 + (((row >> 3) ^ (col & 7)) << 4)
                              + ((row & 7) << 1)) = vv;
                else          // Ts[row 0..63][col 0..383]
                    *(short*)(lds + row * 768 + (((col >> 3) ^ (row & 7)) << 4)
                              + ((col & 7) << 1)) = vv;
            }
    __syncthreads();
    int bb2 = m0 >> 10;
    if (t == 2) {
        #pragma unroll
        for (int j = 0; j < 6; j++) {
            int c = tid * 6 + j;          // 3072 chunks: vr = c>>3, ch = c&7
            int vr = c >> 3, ch = c & 7;
            bf16x8 val = *(const bf16x8*)(lds + vr * 128 + ((ch ^ (vr & 7)) << 4));
            int gc = n0 + vr, h = gc >> 6, dh = gc & 63;
            *(bf16x8*)(v1t + (((size_t)bb2 * H_ + h) * DH_ + dh) * S_
                       + (m0 & 1023) + ch * 8) = val;
        }
    } else {
        short* dst0 = t ? k1 : q1;
        #pragma unroll
        for (int j = 0; j < 6; j++) {
            int c = tid * 6 + j;          // 3072 chunks: row = c/48, ch = c%48
            int row = c / 48, ch = c % 48;
            bf16x8 val = *(const bf16x8*)(lds + row * 768 + ((ch ^ (row & 7)) << 4));
            int m = m0 + row, ss = m & 1023;
            int gc = n0 + ch * 8, h = gc >> 6, dh = gc & 63;
            *(bf16x8*)(dst0 + (((size_t)bb2 * H_ + h) * S_ + ss) * DH_ + dh) = val;
        }
    }
}

// ---------------------------------------------------------------------------
// Kernel 2 (v5): flash attention, swapped-QK^T 32x32x16, block-cooperative
// LDS-staged K/V (unchanged from round 6 -- passing, fast).
// ---------------------------------------------------------------------------
__global__ __launch_bounds__(256, 3) void attn_kernel(
    const short* __restrict__ q1, const short* __restrict__ k1,
    const short* __restrict__ v1t, float* __restrict__ out)
{
    __shared__ short Klds[2][4096];
    __shared__ short Vlds[2][4096];
    __shared__ float lsum_lds[4][32];

    int d    = blockIdx.x;
    int head = (d & 7) + ((d >> 6) << 3);
    int qi   = (d >> 3) & 7;
    int bb   = head / H_, hh = head % H_;

    int tid = threadIdx.x, lane = tid & 63, w = tid >> 6;
    int l31 = lane & 31, hi = lane >> 5;
    int qbase = (qi * 4 + w) * 32;

    const short* Qp = q1  + (size_t)head * S_ * DH_;
    const short* Kp = k1  + (size_t)head * S_ * DH_;
    const short* Vp = v1t + (size_t)head * DH_ * S_;

    int sr = tid >> 2, sc = tid & 3;
    int swz0 = sr * 128 + ((sc       ^ (sr & 7)) << 4);
    int swz1 = sr * 128 + (((sc + 4) ^ (sr & 7)) << 4);

    bf16x8 stK0, stK1, stV0, stV1;

#define LOADST(kvb) do { \
        const short* _kg = Kp + (size_t)((kvb) + sr) * DH_; \
        const short* _vg = Vp + (size_t)sr * S_ + (kvb); \
        stK0 = *(const bf16x8*)(_kg + sc * 8); \
        stK1 = *(const bf16x8*)(_kg + (sc + 4) * 8); \
        stV0 = *(const bf16x8*)(_vg + sc * 8); \
        stV1 = *(const bf16x8*)(_vg + (sc + 4) * 8); \
    } while (0)
#define WRITEST(buf) do { \
        char* _kb = (char*)&Klds[buf][0]; \
        char* _vb = (char*)&Vlds[buf][0]; \
        *(bf16x8*)(_kb + swz0) = stK0; \
        *(bf16x8*)(_kb + swz1) = stK1; \
        *(bf16x8*)(_vb + swz0) = stV0; \
        *(bf16x8*)(_vb + swz1) = stV1; \
    } while (0)

    bf16x8 qf[4];
    #pragma unroll
    for (int kb = 0; kb < 4; kb++)
        qf[kb] = *(const bf16x8*)(Qp + (size_t)(qbase + l31) * DH_ + kb * 16 + hi * 8);

    f32x16 o0, o1;
    #pragma unroll
    for (int r = 0; r < 16; r++) { o0[r] = 0.f; o1[r] = 0.f; }
    float mreg = -1e30f, lsum = 0.f;

    int xk = l31 & 7;

    auto subtile = [&](int cur, int j) {
        const char* Kt = (const char*)&Klds[cur][0];
        const char* Vt = (const char*)&Vlds[cur][0];
        int rK = (32 * j + l31) * 128;
        bf16x8 kf0 = *(const bf16x8*)(Kt + rK + (((0 + hi) ^ xk) << 4));
        bf16x8 kf1 = *(const bf16x8*)(Kt + rK + (((2 + hi) ^ xk) << 4));
        bf16x8 kf2 = *(const bf16x8*)(Kt + rK + (((4 + hi) ^ xk) << 4));
        bf16x8 kf3 = *(const bf16x8*)(Kt + rK + (((6 + hi) ^ xk) << 4));
        int rV0 = l31 * 128, rV1 = (32 + l31) * 128;
        int s0 = ((4 * j + hi) ^ xk) << 4, s1 = ((4 * j + 2 + hi) ^ xk) << 4;
        bf16x8 vf00 = *(const bf16x8*)(Vt + rV0 + s0);
        bf16x8 vf01 = *(const bf16x8*)(Vt + rV0 + s1);
        bf16x8 vf10 = *(const bf16x8*)(Vt + rV1 + s0);
        bf16x8 vf11 = *(const bf16x8*)(Vt + rV1 + s1);

        f32x16 s;
        #pragma unroll
        for (int r = 0; r < 16; r++) s[r] = 0.f;
        __builtin_amdgcn_s_setprio(1);
        s = __builtin_amdgcn_mfma_f32_32x32x16_bf16(kf0, qf[0], s, 0, 0, 0);
        s = __builtin_amdgcn_mfma_f32_32x32x16_bf16(kf1, qf[1], s, 0, 0, 0);
        s = __builtin_amdgcn_mfma_f32_32x32x16_bf16(kf2, qf[2], s, 0, 0, 0);
        s = __builtin_amdgcn_mfma_f32_32x32x16_bf16(kf3, qf[3], s, 0, 0, 0);
        __builtin_amdgcn_s_setprio(0);

        float t0 = fmaxf(s[0], s[1]),   t1 = fmaxf(s[2], s[3]);
        float t2 = fmaxf(s[4], s[5]),   t3 = fmaxf(s[6], s[7]);
        float t4 = fmaxf(s[8], s[9]),   t5 = fmaxf(s[10], s[11]);
        float t6 = fmaxf(s[12], s[13]), t7 = fmaxf(s[14], s[15]);
        float u0 = fmaxf(t0, t1), u1 = fmaxf(t2, t3);
        float u2 = fmaxf(t4, t5), u3 = fmaxf(t6, t7);
        float pmax = fmaxf(fmaxf(u0, u1), fmaxf(u2, u3));
        float2 ph = xhalves(pmax);
        pmax = fmaxf(ph.x, ph.y);

        if (!__all(pmax <= mreg + 8.f)) {
            float mn = fmaxf(mreg, pmax);
            float sc_ = exp2_fast(mreg - mn);
            mreg = mn; lsum *= sc_;
            if (hi == 0) lsum_lds[w][l31] = sc_;
            asm volatile("s_waitcnt lgkmcnt(0)" ::: "memory");
            #pragma unroll
            for (int r = 0; r < 16; r++) {
                int crow = (r & 3) + ((r >> 2) << 3) + (hi << 2);
                float srw = lsum_lds[w][crow];
                o0[r] *= srw; o1[r] *= srw;
            }
        }

        #pragma unroll
        for (int r = 0; r < 16; r++) s[r] = exp2_fast(s[r] - mreg);

        float a0 = s[0] + s[1],   a1 = s[2] + s[3];
        float a2 = s[4] + s[5],   a3 = s[6] + s[7];
        float a4 = s[8] + s[9],   a5 = s[10] + s[11];
        float a6 = s[12] + s[13], a7 = s[14] + s[15];
        float rsum = ((a0 + a1) + (a2 + a3)) + ((a4 + a5) + (a6 + a7));
        float2 rh = xhalves(rsum);
        lsum += rh.x + rh.y;

        unsigned c0 = cvt_pk_bf16(s[0], s[1]);
        unsigned c1 = cvt_pk_bf16(s[2], s[3]);
        unsigned c2 = cvt_pk_bf16(s[4], s[5]);
        unsigned c3 = cvt_pk_bf16(s[6], s[7]);
        unsigned c4 = cvt_pk_bf16(s[8], s[9]);
        unsigned c5 = cvt_pk_bf16(s[10], s[11]);
        unsigned c6 = cvt_pk_bf16(s[12], s[13]);
        unsigned c7 = cvt_pk_bf16(s[14], s[15]);
        plswap(c0, c2);
        plswap(c1, c3);
        plswap(c4, c6);
        plswap(c5, c7);

        union U { unsigned u[4]; bf16x8 v; };
        U f0, f1;
        f0.u[0] = c0; f0.u[1] = c1; f0.u[2] = c2; f0.u[3] = c3;
        f1.u[0] = c4; f1.u[1] = c5; f1.u[2] = c6; f1.u[3] = c7;

        __builtin_amdgcn_s_setprio(1);
        o0 = __builtin_amdgcn_mfma_f32_32x32x16_bf16(f0.v, vf00, o0, 0, 0, 0);
        o0 = __builtin_amdgcn_mfma_f32_32x32x16_bf16(f1.v, vf01, o0, 0, 0, 0);
        o1 = __builtin_amdgcn_mfma_f32_32x32x16_bf16(f0.v, vf10, o1, 0, 0, 0);
        o1 = __builtin_amdgcn_mfma_f32_32x32x16_bf16(f1.v, vf11, o1, 0, 0, 0);
        __builtin_amdgcn_s_setprio(0);
    };

    LOADST(0);
    WRITEST(0);
    LOADST(64);
    asm volatile("s_waitcnt lgkmcnt(0)" ::: "memory");
    __builtin_amdgcn_s_barrier();
    asm volatile("" ::: "memory");

    int cur = 0;
    for (int t = 0; t < 16; t++) {
        if (t < 15) {
            WRITEST(cur ^ 1);
            if (t < 14) LOADST((t + 2) * 64);
        }
        subtile(cur, 0);
        subtile(cur, 1);
        if (t < 15) {
            asm volatile("" ::: "memory");
            asm volatile("s_waitcnt lgkmcnt(0)" ::: "memory");
            __builtin_amdgcn_s_barrier();
            asm volatile("" ::: "memory");
        }
        cur ^= 1;
    }
#undef LOADST
#undef WRITEST

    if (hi == 0) lsum_lds[w][l31] = lsum;
    asm volatile("s_waitcnt lgkmcnt(0)" ::: "memory");
    #pragma unroll
    for (int r = 0; r < 16; r++) {
        int crow = (r & 3) + ((r >> 2) << 3) + (hi << 2);
        float inv = rcp_fast(lsum_lds[w][crow]);
        float* op = out + ((size_t)(bb * S_ + qbase + crow)) * D_ + hh * DH_ + l31;
        op[0]  = o0[r] * inv;
        op[32] = o1[r] * inv;
    }
}

// ---------------------------------------------------------------------------
// Kernel 3 (v2): y = LN(2*out + q) * gamma + beta; 192 thr/row, f32x4 loads.
// ---------------------------------------------------------------------------
__global__ __launch_bounds__(192) void ln_kernel(
    const float* __restrict__ qin, const float* __restrict__ gamma,
    const float* __restrict__ beta, float* __restrict__ out)
{
    int row = blockIdx.x;
    int tid = threadIdx.x;
    size_t base = (size_t)row * D_ + tid * 4;

    f32x4 o  = *(const f32x4*)(out + base);
    f32x4 qv = *(const f32x4*)(qin + base);
    f32x4 x;
    float sum = 0.f, sq = 0.f;
    #pragma unroll
    for (int i = 0; i < 4; i++) {
        x[i] = 2.f * o[i] + qv[i];
        sum += x[i];
        sq  += x[i] * x[i];
    }
    #pragma unroll
    for (int msk = 1; msk < 64; msk <<= 1) {
        sum += __shfl_xor(sum, msk);
        sq  += __shfl_xor(sq, msk);
    }
    __shared__ float s1[3], s2[3];
    if ((tid & 63) == 0) { s1[tid >> 6] = sum; s2[tid >> 6] = sq; }
    __syncthreads();
    sum = s1[0] + s1[1] + s1[2];
    sq  = s2[0] + s2[1] + s2[2];
    float mu   = sum * (1.f / D_);
    float var  = sq * (1.f / D_) - mu * mu;
    float rstd = rsqrtf(var + 1e-5f);
    f32x4 g = *(const f32x4*)(gamma + tid * 4);
    f32x4 b = *(const f32x4*)(beta + tid * 4);
    f32x4 y;
    #pragma unroll
    for (int i = 0; i < 4; i++)
        y[i] = (x[i] - mu) * rstd * g[i] + b[i];
    *(f32x4*)(out + base) = y;
}

// ---------------------------------------------------------------------------
extern "C" void kernel_launch(void* const* d_in, const int* in_sizes, int n_in,
                              void* d_out, int out_size, void* d_ws, size_t ws_size,
                              hipStream_t stream)
{
    const float* q     = (const float*)d_in[0];
    const float* k     = (const float*)d_in[1];
    const float* v     = (const float*)d_in[2];
    const float* W     = (const float*)d_in[3];
    const float* gamma = (const float*)d_in[4];
    const float* beta  = (const float*)d_in[5];

    size_t per = (size_t)B_ * H_ * S_ * DH_;   // 6291456
    short* q1  = (short*)d_ws;
    short* k1  = q1 + per;
    short* v1t = k1 + per;
    short* Wb  = v1t + per;                    // +1.18 MB (total ~38.9 MB)
    float* out = (float*)d_out;

    convw_kernel<<<dim3(288), dim3(256), 0, stream>>>(W, Wb);
    // 384 m-blocks (3 inputs x 128) x 2 n-blocks = 768 blocks, 512 threads
    proj_kernel<<<dim3(768), dim3(512), 0, stream>>>(q, k, v, Wb, q1, k1, v1t);
    attn_kernel<<<dim3(768), dim3(256), 0, stream>>>(q1, k1, v1t, out);
    ln_kernel<<<dim3(B_ * S_), dim3(192), 0, stream>>>(q, gamma, beta, out);
}